// Round 1
// baseline (378.333 us; speedup 1.0000x reference)
//
#include <hip/hip_runtime.h>
#include <hip/hip_bf16.h>
#include <stdint.h>

#define N_NODES 4096
#define HIDDEN 256
#define NHEAD 4
#define DHEAD 64
#define NEDGE 131072
#define MASK_WORDS 128   // 4096 bits / 32

// ---------------------------------------------------------------------------
// Kernel 1: scatter edges + diagonal into a per-row bitmask (dedupes edges).
// ---------------------------------------------------------------------------
__global__ __launch_bounds__(256) void build_mask_kernel(
    const int* __restrict__ eu, const int* __restrict__ ev,
    unsigned int* __restrict__ mask)
{
    int t = blockIdx.x * 256 + threadIdx.x;
    if (t < NEDGE) {
        int u = eu[t], v = ev[t];
        atomicOr(&mask[u * MASK_WORDS + (v >> 5)], 1u << (v & 31));
    } else {
        int i = t - NEDGE;
        if (i < N_NODES)
            atomicOr(&mask[i * MASK_WORDS + (i >> 5)], 1u << (i & 31));
    }
}

// ---------------------------------------------------------------------------
// fp32 tiled GEMM: C(M x 256) = A(M x K) @ B(K x 256) + bias, row-major.
// 64x64 tile, BK=16, 256 threads, 4x4 microtile per thread.
// ---------------------------------------------------------------------------
__device__ __forceinline__ void gemm_tile(
    const float* __restrict__ A, const float* __restrict__ B,
    const float* __restrict__ bias, float* __restrict__ C,
    int K, int bm, int bn,
    float (*As)[68], float (*Bs)[68])
{
    const int tid = threadIdx.x;
    const int tx = tid & 15;   // col group
    const int ty = tid >> 4;   // row group
    float acc[4][4] = {};

    for (int k0 = 0; k0 < K; k0 += 16) {
#pragma unroll
        for (int t = 0; t < 4; ++t) {
            int e = tid + t * 256;          // 0..1023
            int ra = e >> 4, ca = e & 15;   // A tile: 64 rows x 16 cols
            float va = (k0 + ca < K) ? A[(size_t)(bm + ra) * K + k0 + ca] : 0.f;
            As[ca][ra] = va;                // transposed store
            int rb = e >> 6, cb = e & 63;   // B tile: 16 rows x 64 cols
            float vb = (k0 + rb < K) ? B[(size_t)(k0 + rb) * HIDDEN + bn + cb] : 0.f;
            Bs[rb][cb] = vb;
        }
        __syncthreads();
#pragma unroll
        for (int kk = 0; kk < 16; ++kk) {
            float a0 = As[kk][ty * 4 + 0];
            float a1 = As[kk][ty * 4 + 1];
            float a2 = As[kk][ty * 4 + 2];
            float a3 = As[kk][ty * 4 + 3];
            float b0 = Bs[kk][tx * 4 + 0];
            float b1 = Bs[kk][tx * 4 + 1];
            float b2 = Bs[kk][tx * 4 + 2];
            float b3 = Bs[kk][tx * 4 + 3];
            acc[0][0] += a0 * b0; acc[0][1] += a0 * b1; acc[0][2] += a0 * b2; acc[0][3] += a0 * b3;
            acc[1][0] += a1 * b0; acc[1][1] += a1 * b1; acc[1][2] += a1 * b2; acc[1][3] += a1 * b3;
            acc[2][0] += a2 * b0; acc[2][1] += a2 * b1; acc[2][2] += a2 * b2; acc[2][3] += a2 * b3;
            acc[3][0] += a3 * b0; acc[3][1] += a3 * b1; acc[3][2] += a3 * b2; acc[3][3] += a3 * b3;
        }
        __syncthreads();
    }

#pragma unroll
    for (int i = 0; i < 4; ++i) {
        int m = bm + ty * 4 + i;
#pragma unroll
        for (int j = 0; j < 4; ++j) {
            int n = bn + tx * 4 + j;
            C[(size_t)m * HIDDEN + n] = acc[i][j] + bias[n];
        }
    }
}

__global__ __launch_bounds__(256) void gemm_bias_kernel(
    const float* __restrict__ A, const float* __restrict__ B,
    const float* __restrict__ bias, float* __restrict__ C, int K)
{
    __shared__ float As[16][68];
    __shared__ float Bs[16][68];
    gemm_tile(A, B, bias, C, K, blockIdx.y * 64, blockIdx.x * 64, As, Bs);
}

// Fused q/k/v projection: grid.x = 12 column tiles; tiles 0-3 -> q, 4-7 -> k, 8-11 -> v
__global__ __launch_bounds__(256) void gemm_qkv_kernel(
    const float* __restrict__ x,
    const float* __restrict__ Wq, const float* __restrict__ bq,
    const float* __restrict__ Wk, const float* __restrict__ bk,
    const float* __restrict__ Wv, const float* __restrict__ bv,
    float* __restrict__ q, float* __restrict__ k, float* __restrict__ v)
{
    __shared__ float As[16][68];
    __shared__ float Bs[16][68];
    int which = blockIdx.x >> 2;
    const float* B    = (which == 0) ? Wq : (which == 1) ? Wk : Wv;
    const float* bias = (which == 0) ? bq : (which == 1) ? bk : bv;
    float* C          = (which == 0) ? q  : (which == 1) ? k  : v;
    gemm_tile(x, B, bias, C, HIDDEN, blockIdx.y * 64, (blockIdx.x & 3) * 64, As, Bs);
}

// ---------------------------------------------------------------------------
// Kernel 3: sparse masked attention with online softmax.
// One block per row i (256 threads = 4 waves); wave = head, lane = dim.
// ---------------------------------------------------------------------------
__global__ __launch_bounds__(256) void attn_sparse_kernel(
    const float* __restrict__ q, const float* __restrict__ k,
    const float* __restrict__ v, const float* __restrict__ temporal,
    const unsigned int* __restrict__ mask, float* __restrict__ att)
{
    const int i    = blockIdx.x;
    const int h    = threadIdx.x >> 6;
    const int lane = threadIdx.x & 63;

    const float qv = q[(size_t)i * HIDDEN + h * DHEAD + lane];

    float m   = -3.0e38f;  // running max
    float l   = 0.f;       // running denom
    float acc = 0.f;       // running numer (this lane's dim)

    const unsigned int* mrow = mask + (size_t)i * MASK_WORDS;
    const float* trow = temporal + (size_t)i * N_NODES * 2;

    for (int w = 0; w < MASK_WORDS; ++w) {
        unsigned int bits = mrow[w];
        while (bits) {
            int b = __ffs(bits) - 1;
            bits &= bits - 1;
            int j = (w << 5) + b;

            // dot(q_i, k_j) across the 64-lane wave
            float part = qv * k[(size_t)j * HIDDEN + h * DHEAD + lane];
#pragma unroll
            for (int off = 32; off > 0; off >>= 1)
                part += __shfl_xor(part, off, 64);

            // temporal bucket term (identical comparisons to reference)
            float dt = trow[(size_t)j * 2];
            float tb = 0.f;
            tb += 0.2f * (float)((dt >= 0.f)  & (dt <= 5.f));
            tb += 0.1f * (float)((dt >= 5.f)  & (dt <= 15.f));
            tb -= 0.1f * (float)((dt >= 60.f) & (dt <= 240.f));

            float s = part * 0.125f + tb;   // 1/sqrt(64) = 0.125

            // online softmax update (wave-uniform m, l)
            float mn    = fmaxf(m, s);
            float scale = __expf(m - mn);
            float p     = __expf(s - mn);
            l   = l * scale + p;
            acc = acc * scale + p * v[(size_t)j * HIDDEN + h * DHEAD + lane];
            m   = mn;
        }
    }

    att[(size_t)i * HIDDEN + h * DHEAD + lane] = acc / l;
}

// ---------------------------------------------------------------------------
extern "C" void kernel_launch(void* const* d_in, const int* in_sizes, int n_in,
                              void* d_out, int out_size, void* d_ws, size_t ws_size,
                              hipStream_t stream) {
    const float* nf       = (const float*)d_in[0];
    const float* temporal = (const float*)d_in[1];
    const int*   eidx     = (const int*)  d_in[2];
    const float* W_in     = (const float*)d_in[3];
    const float* b_in     = (const float*)d_in[4];
    const float* Wq       = (const float*)d_in[5];
    const float* bq       = (const float*)d_in[6];
    const float* Wk       = (const float*)d_in[7];
    const float* bk       = (const float*)d_in[8];
    const float* Wv       = (const float*)d_in[9];
    const float* bv       = (const float*)d_in[10];
    const float* Wo       = (const float*)d_in[11];
    const float* bo       = (const float*)d_in[12];
    float* out = (float*)d_out;

    char* ws = (char*)d_ws;
    unsigned int* mask = (unsigned int*)(ws);            // 2 MiB
    float* x   = (float*)(ws + (size_t)( 2 << 20));      // 4 MiB
    float* q   = (float*)(ws + (size_t)( 6 << 20));      // 4 MiB
    float* k   = (float*)(ws + (size_t)(10 << 20));      // 4 MiB
    float* v   = (float*)(ws + (size_t)(14 << 20));      // 4 MiB
    float* att = (float*)(ws + (size_t)(18 << 20));      // 4 MiB  (total 22 MiB)

    // 1. adjacency bitmask (workspace is re-poisoned every call -> must zero)
    hipMemsetAsync(mask, 0, (size_t)N_NODES * MASK_WORDS * sizeof(unsigned int), stream);
    build_mask_kernel<<<(NEDGE + N_NODES + 255) / 256, 256, 0, stream>>>(
        eidx, eidx + NEDGE, mask);

    // 2. x = nf @ W_in + b_in   (4096 x 45 -> 4096 x 256)
    gemm_bias_kernel<<<dim3(4, 64), 256, 0, stream>>>(nf, W_in, b_in, x, 45);

    // 3. q,k,v projections (fused launch)
    gemm_qkv_kernel<<<dim3(12, 64), 256, 0, stream>>>(x, Wq, bq, Wk, bk, Wv, bv, q, k, v);

    // 4. sparse masked attention
    attn_sparse_kernel<<<N_NODES, 256, 0, stream>>>(q, k, v, temporal, mask, att);

    // 5. out = att @ Wo + bo
    gemm_bias_kernel<<<dim3(4, 64), 256, 0, stream>>>(att, Wo, bo, out, 256);
}

// Round 2
// 282.054 us; speedup vs baseline: 1.3413x; 1.3413x over previous
//
#include <hip/hip_runtime.h>
#include <hip/hip_bf16.h>
#include <stdint.h>

#define N_NODES 4096
#define HIDDEN 256
#define NHEAD 4
#define DHEAD 64
#define NEDGE 131072
#define MASK_WORDS 128   // 4096 bits / 32
#define KIN 64           // input-proj K padded 45 -> 64

typedef __attribute__((ext_vector_type(8))) short bf16x8;
typedef __attribute__((ext_vector_type(4))) float f32x4;
typedef __hip_bfloat16 bf16;

// ---------------------------------------------------------------------------
// Kernel 1: scatter edges + diagonal into a per-row bitmask (dedupes edges —
// required: duplicate edges must not double-count in the softmax denominator).
// ---------------------------------------------------------------------------
__global__ __launch_bounds__(256) void build_mask_kernel(
    const int* __restrict__ eu, const int* __restrict__ ev,
    unsigned int* __restrict__ mask)
{
    int t = blockIdx.x * 256 + threadIdx.x;
    if (t < NEDGE) {
        int u = eu[t], v = ev[t];
        atomicOr(&mask[u * MASK_WORDS + (v >> 5)], 1u << (v & 31));
    } else {
        int i = t - NEDGE;
        if (i < N_NODES)
            atomicOr(&mask[i * MASK_WORDS + (i >> 5)], 1u << (i & 31));
    }
}

// ---------------------------------------------------------------------------
// Kernel 2: convert inputs/weights to bf16; weights transposed to n-major so
// B-fragments are contiguous 16B loads. nf padded 45->64 cols with zeros.
// ---------------------------------------------------------------------------
__global__ __launch_bounds__(256) void cvt_kernel(
    const float* __restrict__ nf, const float* __restrict__ W_in,
    const float* __restrict__ Wq, const float* __restrict__ Wk,
    const float* __restrict__ Wv, const float* __restrict__ Wo,
    bf16* __restrict__ nfp, bf16* __restrict__ WinT, bf16* __restrict__ WT)
{
    int t = blockIdx.x * 256 + threadIdx.x;
    if (t < N_NODES * KIN) {                       // nfp[row][c], c<45 real
        int row = t >> 6, c = t & 63;
        float v = (c < 45) ? nf[row * 45 + c] : 0.f;
        nfp[t] = __float2bfloat16(v);
    } else if (t < N_NODES * KIN + 256 * KIN) {    // WinT[n][kk] = W_in[kk][n]
        int u = t - N_NODES * KIN;
        int n = u >> 6, kk = u & 63;
        float v = (kk < 45) ? W_in[kk * 256 + n] : 0.f;
        WinT[u] = __float2bfloat16(v);
    } else {                                        // WT[which][n][kk] = W[kk][n]
        int u = t - (N_NODES * KIN + 256 * KIN);
        if (u < 4 * 65536) {
            int which = u >> 16, r = u & 65535;
            int n = r >> 8, kk = r & 255;
            const float* W = (which == 0) ? Wq : (which == 1) ? Wk : (which == 2) ? Wv : Wo;
            WT[u] = __float2bfloat16(W[kk * 256 + n]);
        }
    }
}

// ---------------------------------------------------------------------------
// bf16 MFMA GEMM body: C(M x 256) = A(M x K) @ B + bias.
// A row-major bf16 (contiguous k), Bt n-major bf16 (Bt[n][k]).
// Wave computes a 32x16 strip: 2 A-frags, 1 B-frag, 2 accumulators.
// Frag layout (m89-verified): A[m=lane&15][k=quad*8+j]; D col=lane&15,
// row=quad*4+reg.
// ---------------------------------------------------------------------------
template <bool OUT_BF16>
__device__ __forceinline__ void gemm_body(
    const bf16* __restrict__ A, const bf16* __restrict__ Bt,
    const float* __restrict__ bias, void* __restrict__ Cv,
    int K, int m_base, int n0)
{
    const int lane = threadIdx.x & 63;
    const int row = lane & 15, quad = lane >> 4;
    f32x4 acc0 = {0.f, 0.f, 0.f, 0.f};
    f32x4 acc1 = {0.f, 0.f, 0.f, 0.f};
    const short* Ap = (const short*)A;
    const short* Bp = (const short*)Bt;

    for (int k0 = 0; k0 < K; k0 += 32) {
        bf16x8 b  = *(const bf16x8*)(Bp + (size_t)(n0 + row) * K + k0 + quad * 8);
        bf16x8 a0 = *(const bf16x8*)(Ap + (size_t)(m_base + row) * K + k0 + quad * 8);
        bf16x8 a1 = *(const bf16x8*)(Ap + (size_t)(m_base + 16 + row) * K + k0 + quad * 8);
        acc0 = __builtin_amdgcn_mfma_f32_16x16x32_bf16(a0, b, acc0, 0, 0, 0);
        acc1 = __builtin_amdgcn_mfma_f32_16x16x32_bf16(a1, b, acc1, 0, 0, 0);
    }

    const int col = row;
    const float bval = bias[n0 + col];
#pragma unroll
    for (int e = 0; e < 4; ++e) {
        int m0 = m_base + quad * 4 + e;
        int m1 = m0 + 16;
        float v0 = acc0[e] + bval;
        float v1 = acc1[e] + bval;
        if (OUT_BF16) {
            ((bf16*)Cv)[(size_t)m0 * HIDDEN + n0 + col] = __float2bfloat16(v0);
            ((bf16*)Cv)[(size_t)m1 * HIDDEN + n0 + col] = __float2bfloat16(v1);
        } else {
            ((float*)Cv)[(size_t)m0 * HIDDEN + n0 + col] = v0;
            ((float*)Cv)[(size_t)m1 * HIDDEN + n0 + col] = v1;
        }
    }
}

// x = nfp @ W_in^T' + b_in  (K=64 padded), output bf16
__global__ __launch_bounds__(256) void gemm_in_kernel(
    const bf16* __restrict__ nfp, const bf16* __restrict__ WinT,
    const float* __restrict__ b_in, bf16* __restrict__ x)
{
    int wave = threadIdx.x >> 6;
    gemm_body<true>(nfp, WinT, b_in, x, KIN, blockIdx.y * 128 + wave * 32,
                    blockIdx.x * 16);
}

// q,k,v = x @ {Wq,Wk,Wv} + bias, fp32 outputs. grid.x: [0,48) -> which/ntile
__global__ __launch_bounds__(256) void gemm_qkv_kernel(
    const bf16* __restrict__ x, const bf16* __restrict__ WT,
    const float* __restrict__ bq, const float* __restrict__ bk,
    const float* __restrict__ bv,
    float* __restrict__ q, float* __restrict__ k, float* __restrict__ v)
{
    int which = blockIdx.x >> 4;
    const bf16* Bt = WT + (size_t)which * 65536;
    const float* bias = (which == 0) ? bq : (which == 1) ? bk : bv;
    float* C = (which == 0) ? q : (which == 1) ? k : v;
    int wave = threadIdx.x >> 6;
    gemm_body<false>(x, Bt, bias, C, HIDDEN, blockIdx.y * 128 + wave * 32,
                     (blockIdx.x & 15) * 16);
}

// out = att @ Wo + bo, fp32 output
__global__ __launch_bounds__(256) void gemm_out_kernel(
    const bf16* __restrict__ att, const bf16* __restrict__ WT,
    const float* __restrict__ bo, float* __restrict__ out)
{
    int wave = threadIdx.x >> 6;
    gemm_body<false>(att, WT + (size_t)3 * 65536, bo, out, HIDDEN,
                     blockIdx.y * 128 + wave * 32, blockIdx.x * 16);
}

// ---------------------------------------------------------------------------
// Kernel 4: sparse masked attention, batched x8 for ILP.
// Block = row i (4 waves = 4 heads, lane = dim). Row's valid-j set compacted
// into LDS once, then processed 8 at a time: 8 k/v loads in flight, 8
// interleaved shuffle-reduce chains, one online-softmax rescale per batch.
// ---------------------------------------------------------------------------
__global__ __launch_bounds__(256) void attn_kernel(
    const float* __restrict__ q, const float* __restrict__ k,
    const float* __restrict__ v, const float* __restrict__ temporal,
    const unsigned int* __restrict__ mask, bf16* __restrict__ att)
{
    __shared__ int jlist[4096];   // worst-case degree; 16KB LDS is free here
    __shared__ int cnt;
    const int i = blockIdx.x;
    const int tid = threadIdx.x;

    if (tid == 0) cnt = 0;
    __syncthreads();
    if (tid < MASK_WORDS) {
        unsigned int bits = mask[(size_t)i * MASK_WORDS + tid];
        int n = __popc(bits);
        if (n) {
            int pos = atomicAdd(&cnt, n);
            while (bits) {
                int b = __ffs(bits) - 1;
                bits &= bits - 1;
                jlist[pos++] = (tid << 5) + b;
            }
        }
    }
    __syncthreads();
    const int nn = cnt;   // >= 1 (diagonal always set)

    const int h = tid >> 6, lane = tid & 63;
    const float* trow = temporal + (size_t)i * N_NODES * 2;
    const float qv = q[(size_t)i * HIDDEN + h * DHEAD + lane];

    float m = -3.0e38f, l = 0.f, acc = 0.f;

    for (int b0 = 0; b0 < nn; b0 += 8) {
        int jb[8];
        float kv[8], vv[8], p[8];
#pragma unroll
        for (int bb = 0; bb < 8; ++bb) {
            int idx = b0 + bb;
            jb[bb] = (idx < nn) ? jlist[idx] : -1;
            int j = (jb[bb] >= 0) ? jb[bb] : i;     // dummy -> weight 0 later
            kv[bb] = k[(size_t)j * HIDDEN + h * DHEAD + lane];
            vv[bb] = v[(size_t)j * HIDDEN + h * DHEAD + lane];
        }
#pragma unroll
        for (int bb = 0; bb < 8; ++bb) p[bb] = qv * kv[bb];
        // 8 independent reduction chains, interleaved -> shfl latency hidden
#pragma unroll
        for (int off = 32; off >= 1; off >>= 1) {
#pragma unroll
            for (int bb = 0; bb < 8; ++bb) p[bb] += __shfl_xor(p[bb], off, 64);
        }
        // temporal buckets: lane b fetches dt for batch element b (parallel)
        float tb_mine = 0.f;
        {
            int idx = b0 + lane;
            if (lane < 8 && idx < nn) {
                float dt = trow[(size_t)jlist[idx] * 2];
                tb_mine += 0.2f * (float)((dt >= 0.f) & (dt <= 5.f));
                tb_mine += 0.1f * (float)((dt >= 5.f) & (dt <= 15.f));
                tb_mine -= 0.1f * (float)((dt >= 60.f) & (dt <= 240.f));
            }
        }
        float s[8], bmax = -3.0e38f;
#pragma unroll
        for (int bb = 0; bb < 8; ++bb) {
            float tb = __shfl(tb_mine, bb, 64);
            s[bb] = (jb[bb] >= 0) ? p[bb] * 0.125f + tb : -3.0e38f;
            bmax = fmaxf(bmax, s[bb]);
        }
        float newm = fmaxf(m, bmax);
        float scale = __expf(m - newm);   // first batch: exp(-3e38) = 0, safe
        l *= scale;
        acc *= scale;
#pragma unroll
        for (int bb = 0; bb < 8; ++bb) {
            float pb = __expf(s[bb] - newm);   // invalid -> exp(-huge) = 0
            l += pb;
            acc += pb * vv[bb];
        }
        m = newm;
    }

    att[(size_t)i * HIDDEN + h * DHEAD + lane] = __float2bfloat16(acc / l);
}

// ---------------------------------------------------------------------------
extern "C" void kernel_launch(void* const* d_in, const int* in_sizes, int n_in,
                              void* d_out, int out_size, void* d_ws, size_t ws_size,
                              hipStream_t stream) {
    const float* nf       = (const float*)d_in[0];
    const float* temporal = (const float*)d_in[1];
    const int*   eidx     = (const int*)  d_in[2];
    const float* W_in     = (const float*)d_in[3];
    const float* b_in     = (const float*)d_in[4];
    const float* Wq       = (const float*)d_in[5];
    const float* bq       = (const float*)d_in[6];
    const float* Wk       = (const float*)d_in[7];
    const float* bk       = (const float*)d_in[8];
    const float* Wv       = (const float*)d_in[9];
    const float* bv       = (const float*)d_in[10];
    const float* Wo       = (const float*)d_in[11];
    const float* bo       = (const float*)d_in[12];
    float* out = (float*)d_out;

    char* ws = (char*)d_ws;
    const size_t MiB = 1 << 20;
    unsigned int* mask = (unsigned int*)(ws);                    // 2 MiB
    bf16*  nfp  = (bf16*)(ws + 2 * MiB);                         // 512 KiB
    bf16*  WinT = (bf16*)(ws + 2 * MiB + 512 * 1024);            // 32 KiB
    bf16*  WT   = (bf16*)(ws + 3 * MiB);                         // 512 KiB (4x 256x256)
    bf16*  x    = (bf16*)(ws + 4 * MiB);                         // 2 MiB
    float* q    = (float*)(ws + 6 * MiB);                        // 4 MiB
    float* k    = (float*)(ws + 10 * MiB);                       // 4 MiB
    float* v    = (float*)(ws + 14 * MiB);                       // 4 MiB
    bf16*  att  = (bf16*)(ws + 18 * MiB);                        // 2 MiB -> 20 MiB total

    // 1. adjacency bitmask (ws re-poisoned every call -> must zero)
    hipMemsetAsync(mask, 0, (size_t)N_NODES * MASK_WORDS * sizeof(unsigned int), stream);
    build_mask_kernel<<<(NEDGE + N_NODES + 255) / 256, 256, 0, stream>>>(
        eidx, eidx + NEDGE, mask);

    // 2. bf16 conversions (nf padded, weights transposed)
    {
        int total = N_NODES * KIN + 256 * KIN + 4 * 65536;
        cvt_kernel<<<(total + 255) / 256, 256, 0, stream>>>(
            nf, W_in, Wq, Wk, Wv, Wo, nfp, WinT, WT);
    }

    // 3. x = nf @ W_in + b_in (MFMA, K=64 padded)
    gemm_in_kernel<<<dim3(16, 32), 256, 0, stream>>>(nfp, WinT, b_in, x);

    // 4. q,k,v projections (fused MFMA launch)
    gemm_qkv_kernel<<<dim3(48, 32), 256, 0, stream>>>(x, WT, bq, bk, bv, q, k, v);

    // 5. sparse masked attention (batched x8)
    attn_kernel<<<N_NODES, 256, 0, stream>>>(q, k, v, temporal, mask, att);

    // 6. out = att @ Wo + bo (MFMA)
    gemm_out_kernel<<<dim3(16, 32), 256, 0, stream>>>(att, WT, bo, out);
}

// Round 3
// 260.953 us; speedup vs baseline: 1.4498x; 1.0809x over previous
//
#include <hip/hip_runtime.h>
#include <hip/hip_bf16.h>
#include <stdint.h>

#define N_NODES 4096
#define HIDDEN 256
#define NHEAD 4
#define DHEAD 64
#define NEDGE 131072
#define MASK_WORDS 128   // 4096 bits / 32
#define KIN 64           // input-proj K padded 45 -> 64
#define MAXDEG 1024      // Poisson(32) row degree; >1024 is impossible in practice

typedef __attribute__((ext_vector_type(8))) short bf16x8;
typedef __attribute__((ext_vector_type(4))) float f32x4;
typedef __hip_bfloat16 bf16;

__device__ __forceinline__ float b2f(short s) {
    union { float f; unsigned u; } x;
    x.u = ((unsigned)(unsigned short)s) << 16;
    return x.f;
}

// ---------------------------------------------------------------------------
// Kernel 1 (after memset): fused prep — edge/diag bitmask scatter (dedupes
// duplicate edges: they must not double-count in softmax), nf pad+cvt to bf16,
// weight transpose+cvt to n-major bf16.
// Ranges: [0,NEDGE) edges | [..+N) diag | [..+N*KIN) nfp | [..+256*KIN) WinT
//         | [..+4*65536) WT
// ---------------------------------------------------------------------------
__global__ __launch_bounds__(256) void prep_kernel(
    const int* __restrict__ eidx, const float* __restrict__ nf,
    const float* __restrict__ W_in,
    const float* __restrict__ Wq, const float* __restrict__ Wk,
    const float* __restrict__ Wv, const float* __restrict__ Wo,
    unsigned int* __restrict__ mask, bf16* __restrict__ nfp,
    bf16* __restrict__ WinT, bf16* __restrict__ WT)
{
    int t = blockIdx.x * 256 + threadIdx.x;
    if (t < NEDGE) {
        int u = eidx[t], v = eidx[NEDGE + t];
        atomicOr(&mask[u * MASK_WORDS + (v >> 5)], 1u << (v & 31));
        return;
    }
    t -= NEDGE;
    if (t < N_NODES) {
        atomicOr(&mask[t * MASK_WORDS + (t >> 5)], 1u << (t & 31));
        return;
    }
    t -= N_NODES;
    if (t < N_NODES * KIN) {                    // nfp[row][c], c<45 real
        int row = t >> 6, c = t & 63;
        float v = (c < 45) ? nf[row * 45 + c] : 0.f;
        nfp[t] = __float2bfloat16(v);
        return;
    }
    t -= N_NODES * KIN;
    if (t < 256 * KIN) {                        // WinT[n][kk] = W_in[kk][n]
        int n = t >> 6, kk = t & 63;
        float v = (kk < 45) ? W_in[kk * 256 + n] : 0.f;
        WinT[t] = __float2bfloat16(v);
        return;
    }
    t -= 256 * KIN;
    if (t < 4 * 65536) {                        // WT[which][n][kk] = W[kk][n]
        int which = t >> 16, r = t & 65535;
        int n = r >> 8, kk = r & 255;
        const float* W = (which == 0) ? Wq : (which == 1) ? Wk : (which == 2) ? Wv : Wo;
        WT[t] = __float2bfloat16(W[kk * 256 + n]);
    }
}

// ---------------------------------------------------------------------------
// bf16 MFMA GEMM body: C(M x 256) = A(M x K) @ B + bias.
// A row-major bf16 (contiguous k), Bt n-major bf16 (Bt[n][k]).
// Wave computes a 32x16 strip. Frag layout (m89-verified):
// A[m=lane&15][k=quad*8+j]; D col=lane&15, row=quad*4+reg.
// ---------------------------------------------------------------------------
template <bool OUT_BF16>
__device__ __forceinline__ void gemm_body(
    const bf16* __restrict__ A, const bf16* __restrict__ Bt,
    const float* __restrict__ bias, void* __restrict__ Cv,
    int K, int m_base, int n0)
{
    const int lane = threadIdx.x & 63;
    const int row = lane & 15, quad = lane >> 4;
    f32x4 acc0 = {0.f, 0.f, 0.f, 0.f};
    f32x4 acc1 = {0.f, 0.f, 0.f, 0.f};
    const short* Ap = (const short*)A;
    const short* Bp = (const short*)Bt;

    for (int k0 = 0; k0 < K; k0 += 32) {
        bf16x8 b  = *(const bf16x8*)(Bp + (size_t)(n0 + row) * K + k0 + quad * 8);
        bf16x8 a0 = *(const bf16x8*)(Ap + (size_t)(m_base + row) * K + k0 + quad * 8);
        bf16x8 a1 = *(const bf16x8*)(Ap + (size_t)(m_base + 16 + row) * K + k0 + quad * 8);
        acc0 = __builtin_amdgcn_mfma_f32_16x16x32_bf16(a0, b, acc0, 0, 0, 0);
        acc1 = __builtin_amdgcn_mfma_f32_16x16x32_bf16(a1, b, acc1, 0, 0, 0);
    }

    const int col = row;
    const float bval = bias[n0 + col];
#pragma unroll
    for (int e = 0; e < 4; ++e) {
        int m0 = m_base + quad * 4 + e;
        int m1 = m0 + 16;
        float v0 = acc0[e] + bval;
        float v1 = acc1[e] + bval;
        if (OUT_BF16) {
            ((bf16*)Cv)[(size_t)m0 * HIDDEN + n0 + col] = __float2bfloat16(v0);
            ((bf16*)Cv)[(size_t)m1 * HIDDEN + n0 + col] = __float2bfloat16(v1);
        } else {
            ((float*)Cv)[(size_t)m0 * HIDDEN + n0 + col] = v0;
            ((float*)Cv)[(size_t)m1 * HIDDEN + n0 + col] = v1;
        }
    }
}

// x = nfp @ WinT + b_in  (K=64 padded), output bf16
__global__ __launch_bounds__(256) void gemm_in_kernel(
    const bf16* __restrict__ nfp, const bf16* __restrict__ WinT,
    const float* __restrict__ b_in, bf16* __restrict__ x)
{
    int wave = threadIdx.x >> 6;
    gemm_body<true>(nfp, WinT, b_in, x, KIN, blockIdx.y * 128 + wave * 32,
                    blockIdx.x * 16);
}

// q (fp32), k,v (bf16) projections. grid.x: [0,48) -> which/ntile
__global__ __launch_bounds__(256) void gemm_qkv_kernel(
    const bf16* __restrict__ x, const bf16* __restrict__ WT,
    const float* __restrict__ bq, const float* __restrict__ bk,
    const float* __restrict__ bv,
    float* __restrict__ q, bf16* __restrict__ k, bf16* __restrict__ v)
{
    int which = blockIdx.x >> 4;
    const bf16* Bt = WT + (size_t)which * 65536;
    int wave = threadIdx.x >> 6;
    int mb = blockIdx.y * 128 + wave * 32;
    int n0 = (blockIdx.x & 15) * 16;
    if (which == 0)      gemm_body<false>(x, Bt, bq, q, HIDDEN, mb, n0);
    else if (which == 1) gemm_body<true>(x, Bt, bk, k, HIDDEN, mb, n0);
    else                 gemm_body<true>(x, Bt, bv, v, HIDDEN, mb, n0);
}

// out = att @ Wo + bo, fp32 output
__global__ __launch_bounds__(256) void gemm_out_kernel(
    const bf16* __restrict__ att, const bf16* __restrict__ WT,
    const float* __restrict__ bo, float* __restrict__ out)
{
    int wave = threadIdx.x >> 6;
    gemm_body<false>(att, WT + (size_t)3 * 65536, bo, out, HIDDEN,
                     blockIdx.y * 128 + wave * 32, blockIdx.x * 16);
}

// ---------------------------------------------------------------------------
// Kernel 4: sparse masked attention, transposed parallelization.
// Block = row i; wave = head. Phase A: lane = neighbor j (private dot via LDS
// q broadcast, one expf per lane, 12 shfls per 64-j chunk). Phase B: lane =
// dim (p broadcast from LDS, pipelined bf16 v loads). Online softmax across
// chunks (typical degree ~33 -> one chunk).
// ---------------------------------------------------------------------------
__global__ __launch_bounds__(256) void attn_kernel(
    const float* __restrict__ q, const bf16* __restrict__ k,
    const bf16* __restrict__ v, const float* __restrict__ temporal,
    const unsigned int* __restrict__ mask, bf16* __restrict__ att)
{
    __shared__ int jlist[MAXDEG];
    __shared__ float qs[HIDDEN];
    __shared__ float pj[NHEAD][64];
    __shared__ int cnt;
    const int i = blockIdx.x, tid = threadIdx.x;

    if (tid == 0) cnt = 0;
    qs[tid] = q[(size_t)i * HIDDEN + tid];
    __syncthreads();
    if (tid < MASK_WORDS) {
        unsigned int bits = mask[(size_t)i * MASK_WORDS + tid];
        int n = __popc(bits);
        if (n) {
            int pos = atomicAdd(&cnt, n);
            while (bits) {
                int b = __ffs(bits) - 1;
                bits &= bits - 1;
                if (pos < MAXDEG) jlist[pos] = (tid << 5) + b;
                ++pos;
            }
        }
    }
    __syncthreads();
    const int nn = cnt;   // >= 1 (diagonal always set)

    const int h = tid >> 6, lane = tid & 63;
    const float* trow = temporal + (size_t)i * N_NODES * 2;
    const short* kp = (const short*)k;
    const short* vp = (const short*)v;
    const float* qh = qs + h * DHEAD;

    float m = -3.0e38f, l = 0.f, acc = 0.f;

    for (int c0 = 0; c0 < nn; c0 += 64) {
        const int cend = min(64, nn - c0);
        // ---- Phase A: lane jj scores neighbor jlist[c0+jj] ----
        float s = -3.0e38f;
        if (lane < cend) {
            int j = jlist[c0 + lane];
            float dt = trow[(size_t)j * 2];
            const short* krow = kp + (size_t)j * HIDDEN + h * DHEAD;
            bf16x8 k8[8];
#pragma unroll
            for (int t = 0; t < 8; ++t)
                k8[t] = *(const bf16x8*)(krow + t * 8);
            float dot = 0.f;
#pragma unroll
            for (int t = 0; t < 8; ++t)
#pragma unroll
                for (int e = 0; e < 8; ++e)
                    dot += b2f(k8[t][e]) * qh[t * 8 + e];
            float tb = 0.f;
            tb += 0.2f * (float)((dt >= 0.f)  & (dt <= 5.f));
            tb += 0.1f * (float)((dt >= 5.f)  & (dt <= 15.f));
            tb -= 0.1f * (float)((dt >= 60.f) & (dt <= 240.f));
            s = dot * 0.125f + tb;
        }
        float cmax = s;
#pragma unroll
        for (int off = 32; off >= 1; off >>= 1)
            cmax = fmaxf(cmax, __shfl_xor(cmax, off, 64));
        float newm = fmaxf(m, cmax);          // finite after first chunk
        float scale = __expf(m - newm);       // first chunk: exp(-inf)=0
        float p = __expf(s - newm);           // invalid lanes -> 0
        float csum = p;
#pragma unroll
        for (int off = 32; off >= 1; off >>= 1)
            csum += __shfl_xor(csum, off, 64);
        pj[h][lane] = p;                      // wave-private slice, no barrier
        l = l * scale + csum;
        // ---- Phase B: lane = dim, accumulate p_j * v_j ----
        acc *= scale;
        for (int u = 0; u < cend; u += 8) {
#pragma unroll
            for (int t = 0; t < 8; ++t) {
                int idx = u + t;
                bool valid = idx < cend;
                int j = jlist[c0 + (valid ? idx : 0)];
                float pv = valid ? pj[h][idx] : 0.f;
                float vf = b2f(vp[(size_t)j * HIDDEN + h * DHEAD + lane]);
                acc += pv * vf;
            }
        }
        m = newm;
    }

    att[(size_t)i * HIDDEN + h * DHEAD + lane] = __float2bfloat16(acc / l);
}

// ---------------------------------------------------------------------------
extern "C" void kernel_launch(void* const* d_in, const int* in_sizes, int n_in,
                              void* d_out, int out_size, void* d_ws, size_t ws_size,
                              hipStream_t stream) {
    const float* nf       = (const float*)d_in[0];
    const float* temporal = (const float*)d_in[1];
    const int*   eidx     = (const int*)  d_in[2];
    const float* W_in     = (const float*)d_in[3];
    const float* b_in     = (const float*)d_in[4];
    const float* Wq       = (const float*)d_in[5];
    const float* bq       = (const float*)d_in[6];
    const float* Wk       = (const float*)d_in[7];
    const float* bk       = (const float*)d_in[8];
    const float* Wv       = (const float*)d_in[9];
    const float* bv       = (const float*)d_in[10];
    const float* Wo       = (const float*)d_in[11];
    const float* bo       = (const float*)d_in[12];
    float* out = (float*)d_out;

    char* ws = (char*)d_ws;
    const size_t MiB = 1 << 20;
    unsigned int* mask = (unsigned int*)(ws);                 // 2 MiB
    bf16*  nfp  = (bf16*)(ws + 2 * MiB);                      // 512 KiB
    bf16*  WinT = (bf16*)(ws + 2 * MiB + 512 * 1024);         // 32 KiB
    bf16*  WT   = (bf16*)(ws + 3 * MiB);                      // 512 KiB (4x 256x256)
    bf16*  x    = (bf16*)(ws + 4 * MiB);                      // 2 MiB
    float* q    = (float*)(ws + 6 * MiB);                     // 4 MiB
    bf16*  kb   = (bf16*)(ws + 10 * MiB);                     // 2 MiB
    bf16*  vb   = (bf16*)(ws + 12 * MiB);                     // 2 MiB
    bf16*  att  = (bf16*)(ws + 14 * MiB);                     // 2 MiB -> 16 MiB total

    // 1. zero the bitmask (ws is re-poisoned to 0xAA every call)
    hipMemsetAsync(mask, 0, (size_t)N_NODES * MASK_WORDS * sizeof(unsigned int), stream);

    // 2. fused prep: mask scatter + diag + nf pad/cvt + weight transpose/cvt
    {
        int total = NEDGE + N_NODES + N_NODES * KIN + 256 * KIN + 4 * 65536;
        prep_kernel<<<(total + 255) / 256, 256, 0, stream>>>(
            eidx, nf, W_in, Wq, Wk, Wv, Wo, mask, nfp, WinT, WT);
    }

    // 3. x = nf @ W_in + b_in (MFMA, K=64 padded)
    gemm_in_kernel<<<dim3(16, 32), 256, 0, stream>>>(nfp, WinT, b_in, x);

    // 4. q,k,v projections (fused MFMA launch; k,v in bf16)
    gemm_qkv_kernel<<<dim3(48, 32), 256, 0, stream>>>(x, WT, bq, bk, bv, q, kb, vb);

    // 5. sparse masked attention (j-parallel scoring / dim-parallel PV)
    attn_kernel<<<N_NODES, 256, 0, stream>>>(q, kb, vb, temporal, mask, att);

    // 6. out = att @ Wo + bo (MFMA)
    gemm_out_kernel<<<dim3(16, 32), 256, 0, stream>>>(att, WT, bo, out);
}

// Round 4
// 250.927 us; speedup vs baseline: 1.5077x; 1.0400x over previous
//
#include <hip/hip_runtime.h>
#include <hip/hip_bf16.h>
#include <stdint.h>

#define N_NODES 4096
#define HIDDEN 256
#define NHEAD 4
#define DHEAD 64
#define NEDGE 131072
#define MASK_WORDS 128   // 4096 bits / 32
#define KIN 64           // combined-proj K padded 45 -> 64
#define MAXDEG 1024      // Poisson(~33) row degree; >1024 impossible in practice

typedef __attribute__((ext_vector_type(8))) short bf16x8;
typedef __attribute__((ext_vector_type(4))) float f32x4;
typedef __hip_bfloat16 bf16;

__device__ __forceinline__ float b2f(short s) {
    union { float f; unsigned u; } x;
    x.u = ((unsigned)(unsigned short)s) << 16;
    return x.f;
}

// ---------------------------------------------------------------------------
// Kernel 1 (after mask memset): fused prep.
//  R0: edge scatter into bitmask (dedupe: duplicate edges must not
//      double-count in softmax)         [NEDGE]
//  R1: diagonal bits                    [N_NODES]
//  R2: nf pad 45->64 + cvt bf16         [N_NODES*KIN]
//  R3: combined weights W'q/k/v = W_in @ W  (fp32 dot, bf16 n-major store,
//      kk padded to 64)                 [3*256*64]
//  R4: combined biases b' = b_in @ W + b (fp32)  [3*256]
//  R5: Wo transpose+cvt (n-major)       [65536]
// ---------------------------------------------------------------------------
__global__ __launch_bounds__(256) void prep_kernel(
    const int* __restrict__ eidx, const float* __restrict__ nf,
    const float* __restrict__ W_in, const float* __restrict__ b_in,
    const float* __restrict__ Wq, const float* __restrict__ bq,
    const float* __restrict__ Wk, const float* __restrict__ bk,
    const float* __restrict__ Wv, const float* __restrict__ bv,
    const float* __restrict__ Wo,
    unsigned int* __restrict__ mask, bf16* __restrict__ nfp,
    bf16* __restrict__ WqkvT, float* __restrict__ bqkv,
    bf16* __restrict__ WoT)
{
    int t = blockIdx.x * 256 + threadIdx.x;
    if (t < NEDGE) {
        int u = eidx[t], v = eidx[NEDGE + t];
        atomicOr(&mask[u * MASK_WORDS + (v >> 5)], 1u << (v & 31));
        return;
    }
    t -= NEDGE;
    if (t < N_NODES) {
        atomicOr(&mask[t * MASK_WORDS + (t >> 5)], 1u << (t & 31));
        return;
    }
    t -= N_NODES;
    if (t < N_NODES * KIN) {                    // nfp[row][c]
        int row = t >> 6, c = t & 63;
        float v = (c < 45) ? nf[row * 45 + c] : 0.f;
        nfp[t] = __float2bfloat16(v);
        return;
    }
    t -= N_NODES * KIN;
    if (t < 3 * 256 * KIN) {                    // W'T[which][n][kk]
        int which = t >> 14, r = t & 16383;
        int n = r & 255, kk = r >> 8;           // consecutive t -> consecutive n
        const float* W = (which == 0) ? Wq : (which == 1) ? Wk : Wv;
        float dot = 0.f;
        if (kk < 45) {
            const float* wrow = W_in + kk * 256;   // broadcast across n-threads
            for (int c = 0; c < 256; ++c)
                dot += wrow[c] * W[c * 256 + n];   // coalesced in n
        }
        WqkvT[(size_t)which * 16384 + (size_t)n * KIN + kk] = __float2bfloat16(dot);
        return;
    }
    t -= 3 * 256 * KIN;
    if (t < 3 * 256) {                          // b'[which][n]
        int which = t >> 8, n = t & 255;
        const float* W = (which == 0) ? Wq : (which == 1) ? Wk : Wv;
        const float* b = (which == 0) ? bq : (which == 1) ? bk : bv;
        float acc = b[n];
        for (int c = 0; c < 256; ++c)
            acc += b_in[c] * W[c * 256 + n];
        bqkv[t] = acc;
        return;
    }
    t -= 3 * 256;
    if (t < 65536) {                            // WoT[n][kk] = Wo[kk][n]
        int kk = t >> 8, n = t & 255;           // coalesced read of Wo
        WoT[(size_t)n * 256 + kk] = __float2bfloat16(Wo[(size_t)kk * 256 + n]);
    }
}

// ---------------------------------------------------------------------------
// bf16 MFMA GEMM body: C(M x 256) = A(M x K) @ Bt^T + bias.
// A row-major bf16, Bt n-major bf16 (Bt[n][k]). Wave = 32x16 strip.
// Frag layout (m89-verified): A[m=lane&15][k=quad*8+j]; D col=lane&15,
// row=quad*4+reg.
// ---------------------------------------------------------------------------
template <bool OUT_BF16>
__device__ __forceinline__ void gemm_body(
    const bf16* __restrict__ A, const bf16* __restrict__ Bt,
    const float* __restrict__ bias, void* __restrict__ Cv,
    int K, int m_base, int n0)
{
    const int lane = threadIdx.x & 63;
    const int row = lane & 15, quad = lane >> 4;
    f32x4 acc0 = {0.f, 0.f, 0.f, 0.f};
    f32x4 acc1 = {0.f, 0.f, 0.f, 0.f};
    const short* Ap = (const short*)A;
    const short* Bp = (const short*)Bt;

    for (int k0 = 0; k0 < K; k0 += 32) {
        bf16x8 b  = *(const bf16x8*)(Bp + (size_t)(n0 + row) * K + k0 + quad * 8);
        bf16x8 a0 = *(const bf16x8*)(Ap + (size_t)(m_base + row) * K + k0 + quad * 8);
        bf16x8 a1 = *(const bf16x8*)(Ap + (size_t)(m_base + 16 + row) * K + k0 + quad * 8);
        acc0 = __builtin_amdgcn_mfma_f32_16x16x32_bf16(a0, b, acc0, 0, 0, 0);
        acc1 = __builtin_amdgcn_mfma_f32_16x16x32_bf16(a1, b, acc1, 0, 0, 0);
    }

    const int col = row;
    const float bval = bias[n0 + col];
#pragma unroll
    for (int e = 0; e < 4; ++e) {
        int m0 = m_base + quad * 4 + e;
        int m1 = m0 + 16;
        float v0 = acc0[e] + bval;
        float v1 = acc1[e] + bval;
        if (OUT_BF16) {
            ((bf16*)Cv)[(size_t)m0 * HIDDEN + n0 + col] = __float2bfloat16(v0);
            ((bf16*)Cv)[(size_t)m1 * HIDDEN + n0 + col] = __float2bfloat16(v1);
        } else {
            ((float*)Cv)[(size_t)m0 * HIDDEN + n0 + col] = v0;
            ((float*)Cv)[(size_t)m1 * HIDDEN + n0 + col] = v1;
        }
    }
}

// q (fp32), k,v (bf16) = nfp @ W' + b'  (K=64). grid.x: [0,48) -> which/ntile
__global__ __launch_bounds__(256) void gemm_qkv_kernel(
    const bf16* __restrict__ nfp, const bf16* __restrict__ WqkvT,
    const float* __restrict__ bqkv,
    float* __restrict__ q, bf16* __restrict__ k, bf16* __restrict__ v)
{
    int which = blockIdx.x >> 4;
    const bf16* Bt = WqkvT + (size_t)which * 16384;
    const float* bias = bqkv + which * 256;
    int wave = threadIdx.x >> 6;
    int mb = blockIdx.y * 128 + wave * 32;
    int n0 = (blockIdx.x & 15) * 16;
    if (which == 0)      gemm_body<false>(nfp, Bt, bias, q, KIN, mb, n0);
    else if (which == 1) gemm_body<true>(nfp, Bt, bias, k, KIN, mb, n0);
    else                 gemm_body<true>(nfp, Bt, bias, v, KIN, mb, n0);
}

// out = att @ Wo + bo, fp32 output
__global__ __launch_bounds__(256) void gemm_out_kernel(
    const bf16* __restrict__ att, const bf16* __restrict__ WoT,
    const float* __restrict__ bo, float* __restrict__ out)
{
    int wave = threadIdx.x >> 6;
    gemm_body<false>(att, WoT, bo, out, HIDDEN,
                     blockIdx.y * 128 + wave * 32, blockIdx.x * 16);
}

// ---------------------------------------------------------------------------
// Kernel 3: sparse masked attention. Block = row i; wave = head.
// No max-shift: |s| <= ~30 (unit-variance dots /8 + 0.2 bucket), exp(s) is
// fp32-safe; softmax is shift-invariant so result is identical. Phase A:
// lane = neighbor (private dot from LDS q broadcast, one expf). Phase B:
// lane = dim (p broadcast from LDS, coalesced bf16 v loads).
// ---------------------------------------------------------------------------
__global__ __launch_bounds__(256) void attn_kernel(
    const float* __restrict__ q, const bf16* __restrict__ k,
    const bf16* __restrict__ v, const float* __restrict__ temporal,
    const unsigned int* __restrict__ mask, bf16* __restrict__ att)
{
    __shared__ int jlist[MAXDEG];
    __shared__ float qs[HIDDEN];
    __shared__ float pj[NHEAD][64];
    __shared__ int cnt;
    const int i = blockIdx.x, tid = threadIdx.x;

    if (tid == 0) cnt = 0;
    qs[tid] = q[(size_t)i * HIDDEN + tid];
    __syncthreads();
    if (tid < MASK_WORDS) {
        unsigned int bits = mask[(size_t)i * MASK_WORDS + tid];
        int n = __popc(bits);
        if (n) {
            int pos = atomicAdd(&cnt, n);
            while (bits) {
                int b = __ffs(bits) - 1;
                bits &= bits - 1;
                if (pos < MAXDEG) jlist[pos] = (tid << 5) + b;
                ++pos;
            }
        }
    }
    __syncthreads();
    const int nn = cnt;   // >= 1 (diagonal always set)

    const int h = tid >> 6, lane = tid & 63;
    const float* trow = temporal + (size_t)i * N_NODES * 2;
    const short* kp = (const short*)k;
    const short* vp = (const short*)v;
    const float* qh = qs + h * DHEAD;

    float l = 0.f, acc = 0.f;

    for (int c0 = 0; c0 < nn; c0 += 64) {
        const int cend = min(64, nn - c0);
        // ---- Phase A: lane scores neighbor jlist[c0+lane] ----
        float s = -3.0e38f;                   // exp -> 0 for invalid lanes
        if (lane < cend) {
            int j = jlist[c0 + lane];
            float dt = trow[(size_t)j * 2];
            const short* krow = kp + (size_t)j * HIDDEN + h * DHEAD;
            bf16x8 k8[8];
#pragma unroll
            for (int t = 0; t < 8; ++t)
                k8[t] = *(const bf16x8*)(krow + t * 8);
            float dot = 0.f;
#pragma unroll
            for (int t = 0; t < 8; ++t)
#pragma unroll
                for (int e = 0; e < 8; ++e)
                    dot += b2f(k8[t][e]) * qh[t * 8 + e];
            float tb = 0.f;
            tb += 0.2f * (float)((dt >= 0.f)  & (dt <= 5.f));
            tb += 0.1f * (float)((dt >= 5.f)  & (dt <= 15.f));
            tb -= 0.1f * (float)((dt >= 60.f) & (dt <= 240.f));
            s = dot * 0.125f + tb;
        }
        float p = __expf(s);
        float csum = p;
#pragma unroll
        for (int off = 32; off >= 1; off >>= 1)
            csum += __shfl_xor(csum, off, 64);
        pj[h][lane] = p;                      // wave-private slice, no barrier
        l += csum;
        // ---- Phase B: lane = dim, accumulate p_j * v_j ----
        for (int u = 0; u < cend; u += 8) {
#pragma unroll
            for (int t = 0; t < 8; ++t) {
                int idx = u + t;
                bool valid = idx < cend;
                int j = jlist[c0 + (valid ? idx : 0)];
                float pv = valid ? pj[h][idx] : 0.f;
                float vf = b2f(vp[(size_t)j * HIDDEN + h * DHEAD + lane]);
                acc += pv * vf;
            }
        }
    }

    att[(size_t)i * HIDDEN + h * DHEAD + lane] = __float2bfloat16(acc / l);
}

// ---------------------------------------------------------------------------
extern "C" void kernel_launch(void* const* d_in, const int* in_sizes, int n_in,
                              void* d_out, int out_size, void* d_ws, size_t ws_size,
                              hipStream_t stream) {
    const float* nf       = (const float*)d_in[0];
    const float* temporal = (const float*)d_in[1];
    const int*   eidx     = (const int*)  d_in[2];
    const float* W_in     = (const float*)d_in[3];
    const float* b_in     = (const float*)d_in[4];
    const float* Wq       = (const float*)d_in[5];
    const float* bq       = (const float*)d_in[6];
    const float* Wk       = (const float*)d_in[7];
    const float* bk       = (const float*)d_in[8];
    const float* Wv       = (const float*)d_in[9];
    const float* bv       = (const float*)d_in[10];
    const float* Wo       = (const float*)d_in[11];
    const float* bo       = (const float*)d_in[12];
    float* out = (float*)d_out;

    char* ws = (char*)d_ws;
    const size_t MiB = 1 << 20, KiB = 1 << 10;
    unsigned int* mask = (unsigned int*)(ws);                  // 2 MiB
    bf16*  nfp   = (bf16*)(ws + 2 * MiB);                      // 512 KiB
    bf16*  WqkvT = (bf16*)(ws + 2 * MiB + 512 * KiB);          // 96 KiB
    float* bqkv  = (float*)(ws + 2 * MiB + 640 * KiB);         // 3 KiB
    bf16*  WoT   = (bf16*)(ws + 3 * MiB);                      // 128 KiB
    float* q     = (float*)(ws + 4 * MiB);                     // 4 MiB
    bf16*  kb    = (bf16*)(ws + 8 * MiB);                      // 2 MiB
    bf16*  vb    = (bf16*)(ws + 10 * MiB);                     // 2 MiB
    bf16*  att   = (bf16*)(ws + 12 * MiB);                     // 2 MiB -> 14 MiB

    // 1. zero the bitmask (ws re-poisoned to 0xAA every call)
    hipMemsetAsync(mask, 0, (size_t)N_NODES * MASK_WORDS * sizeof(unsigned int), stream);

    // 2. fused prep: mask scatter + nf cvt + combined W'/b' + Wo transpose
    {
        int total = NEDGE + N_NODES + N_NODES * KIN + 3 * 256 * KIN + 3 * 256 + 65536;
        prep_kernel<<<(total + 255) / 256, 256, 0, stream>>>(
            eidx, nf, W_in, b_in, Wq, bq, Wk, bk, Wv, bv, Wo,
            mask, nfp, WqkvT, bqkv, WoT);
    }

    // 3. q,k,v = nf @ W' + b' (MFMA, K=64; input projection folded in)
    gemm_qkv_kernel<<<dim3(48, 32), 256, 0, stream>>>(nfp, WqkvT, bqkv, q, kb, vb);

    // 4. sparse masked attention (no-shift softmax)
    attn_kernel<<<N_NODES, 256, 0, stream>>>(q, kb, vb, temporal, mask, att);

    // 5. out = att @ Wo + bo (MFMA)
    gemm_out_kernel<<<dim3(16, 32), 256, 0, stream>>>(att, WoT, bo, out);
}

// Round 5
// 247.233 us; speedup vs baseline: 1.5303x; 1.0149x over previous
//
#include <hip/hip_runtime.h>
#include <hip/hip_bf16.h>
#include <stdint.h>

#define N_NODES 4096
#define HIDDEN 256
#define NHEAD 4
#define DHEAD 64
#define NEDGE 131072
#define MASK_WORDS 128   // 4096 bits / 32
#define KIN 64           // combined-proj K padded 45 -> 64
#define MAXDEG 1024      // Poisson(~33) row degree; >1024 impossible in practice

typedef __attribute__((ext_vector_type(8))) short bf16x8;
typedef __attribute__((ext_vector_type(4))) float f32x4;
typedef __hip_bfloat16 bf16;

__device__ __forceinline__ float b2f(unsigned short s) {
    union { float f; unsigned u; } x;
    x.u = ((unsigned)s) << 16;
    return x.f;
}
__device__ __forceinline__ unsigned short f2bu(float f) {
    bf16 b = __float2bfloat16(f);
    return *(unsigned short*)&b;
}

// ---------------------------------------------------------------------------
// Dispatch 1: prep — mask zero (uint4), nf pad+cvt, combined W'/b', WoT.
//  R0: mask zero as uint4              [131072]
//  R1: nf pad 45->64 + cvt bf16        [N_NODES*KIN = 262144]
//  R2: W'q/k/v = W_in @ W (fp32 dot, bf16 n-major, kk padded)  [3*256*64]
//  R3: b' = b_in @ W + b               [3*256]
//  R4: WoT transpose+cvt (n-major)     [65536]
// Zero->scatter ordering is provided by the dispatch boundary (scatter is in
// dispatch 2).
// ---------------------------------------------------------------------------
__global__ __launch_bounds__(256) void prep_kernel(
    const float* __restrict__ nf,
    const float* __restrict__ W_in, const float* __restrict__ b_in,
    const float* __restrict__ Wq, const float* __restrict__ bq,
    const float* __restrict__ Wk, const float* __restrict__ bk,
    const float* __restrict__ Wv, const float* __restrict__ bv,
    const float* __restrict__ Wo,
    unsigned int* __restrict__ mask, bf16* __restrict__ nfp,
    bf16* __restrict__ WqkvT, float* __restrict__ bqkv,
    bf16* __restrict__ WoT)
{
    int t = blockIdx.x * 256 + threadIdx.x;
    if (t < 131072) {                           // 2 MiB mask zero, 16B/thread
        ((uint4*)mask)[t] = make_uint4(0, 0, 0, 0);
        return;
    }
    t -= 131072;
    if (t < N_NODES * KIN) {                    // nfp[row][c]
        int row = t >> 6, c = t & 63;
        float v = (c < 45) ? nf[row * 45 + c] : 0.f;
        nfp[t] = __float2bfloat16(v);
        return;
    }
    t -= N_NODES * KIN;
    if (t < 3 * 256 * KIN) {                    // W'T[which][n][kk]
        int which = t >> 14, r = t & 16383;
        int n = r & 255, kk = r >> 8;           // consecutive t -> consecutive n
        const float* W = (which == 0) ? Wq : (which == 1) ? Wk : Wv;
        float dot = 0.f;
        if (kk < 45) {
            const float* wrow = W_in + kk * 256;   // broadcast across n-threads
            for (int c = 0; c < 256; ++c)
                dot += wrow[c] * W[c * 256 + n];   // coalesced in n
        }
        WqkvT[(size_t)which * 16384 + (size_t)n * KIN + kk] = __float2bfloat16(dot);
        return;
    }
    t -= 3 * 256 * KIN;
    if (t < 3 * 256) {                          // b'[which][n]
        int which = t >> 8, n = t & 255;
        const float* W = (which == 0) ? Wq : (which == 1) ? Wk : Wv;
        const float* b = (which == 0) ? bq : (which == 1) ? bk : bv;
        float acc = b[n];
        for (int c = 0; c < 256; ++c)
            acc += b_in[c] * W[c * 256 + n];
        bqkv[t] = acc;
        return;
    }
    t -= 3 * 256;
    if (t < 65536) {                            // WoT[n][kk] = Wo[kk][n]
        int kk = t >> 8, n = t & 255;           // coalesced read of Wo
        WoT[(size_t)n * 256 + kk] = __float2bfloat16(Wo[(size_t)kk * 256 + n]);
    }
}

// ---------------------------------------------------------------------------
// bf16 MFMA GEMM body: C(M x 256) = A(M x K) @ Bt^T + bias.
// A row-major bf16, Bt n-major bf16 (Bt[n][k]). Wave = 32x16 strip.
// Frag layout (m89-verified): A[m=lane&15][k=quad*8+j]; D col=lane&15,
// row=quad*4+reg.
// ---------------------------------------------------------------------------
template <bool OUT_BF16>
__device__ __forceinline__ void gemm_body(
    const bf16* __restrict__ A, const bf16* __restrict__ Bt,
    const float* __restrict__ bias, void* __restrict__ Cv,
    int K, int m_base, int n0)
{
    const int lane = threadIdx.x & 63;
    const int row = lane & 15, quad = lane >> 4;
    f32x4 acc0 = {0.f, 0.f, 0.f, 0.f};
    f32x4 acc1 = {0.f, 0.f, 0.f, 0.f};
    const short* Ap = (const short*)A;
    const short* Bp = (const short*)Bt;

    for (int k0 = 0; k0 < K; k0 += 32) {
        bf16x8 b  = *(const bf16x8*)(Bp + (size_t)(n0 + row) * K + k0 + quad * 8);
        bf16x8 a0 = *(const bf16x8*)(Ap + (size_t)(m_base + row) * K + k0 + quad * 8);
        bf16x8 a1 = *(const bf16x8*)(Ap + (size_t)(m_base + 16 + row) * K + k0 + quad * 8);
        acc0 = __builtin_amdgcn_mfma_f32_16x16x32_bf16(a0, b, acc0, 0, 0, 0);
        acc1 = __builtin_amdgcn_mfma_f32_16x16x32_bf16(a1, b, acc1, 0, 0, 0);
    }

    const int col = row;
    const float bval = bias[n0 + col];
#pragma unroll
    for (int e = 0; e < 4; ++e) {
        int m0 = m_base + quad * 4 + e;
        int m1 = m0 + 16;
        float v0 = acc0[e] + bval;
        float v1 = acc1[e] + bval;
        if (OUT_BF16) {
            ((bf16*)Cv)[(size_t)m0 * HIDDEN + n0 + col] = __float2bfloat16(v0);
            ((bf16*)Cv)[(size_t)m1 * HIDDEN + n0 + col] = __float2bfloat16(v1);
        } else {
            ((float*)Cv)[(size_t)m0 * HIDDEN + n0 + col] = v0;
            ((float*)Cv)[(size_t)m1 * HIDDEN + n0 + col] = v1;
        }
    }
}

// ---------------------------------------------------------------------------
// Dispatch 2: QKV MFMA GEMM + edge/diag bitmask scatter (independent work;
// scatter sees a zeroed mask from dispatch 1). Blocks [0,1536): GEMM tiles
// (bx = ntile*32 + mrow); blocks [1536,2064): scatter.
// Bitmask dedupes duplicate edges (must not double-count in softmax).
// ---------------------------------------------------------------------------
__global__ __launch_bounds__(256) void qkv_scatter_kernel(
    const bf16* __restrict__ nfp, const bf16* __restrict__ WqkvT,
    const float* __restrict__ bqkv, const int* __restrict__ eidx,
    float* __restrict__ q, bf16* __restrict__ k, bf16* __restrict__ v,
    unsigned int* __restrict__ mask)
{
    int bx = blockIdx.x;
    if (bx < 1536) {
        int ntile = bx >> 5, mrow = bx & 31;
        int which = ntile >> 4;
        const bf16* Bt = WqkvT + (size_t)which * 16384;
        const float* bias = bqkv + which * 256;
        int wave = threadIdx.x >> 6;
        int mb = mrow * 128 + wave * 32;
        int n0 = (ntile & 15) * 16;
        if (which == 0)      gemm_body<false>(nfp, Bt, bias, q, KIN, mb, n0);
        else if (which == 1) gemm_body<true>(nfp, Bt, bias, k, KIN, mb, n0);
        else                 gemm_body<true>(nfp, Bt, bias, v, KIN, mb, n0);
        return;
    }
    int t = (bx - 1536) * 256 + threadIdx.x;
    if (t < NEDGE) {
        int u = eidx[t], w = eidx[NEDGE + t];
        atomicOr(&mask[u * MASK_WORDS + (w >> 5)], 1u << (w & 31));
    } else {
        int i = t - NEDGE;
        if (i < N_NODES)
            atomicOr(&mask[i * MASK_WORDS + (i >> 5)], 1u << (i & 31));
    }
}

// ---------------------------------------------------------------------------
// Dispatch 3: sparse masked attention. Block = row i; wave = head.
// No max-shift: |s| <= ~30, exp(s) fp32-safe; softmax shift-invariant.
// Phase A: lane = neighbor (private dot from LDS q broadcast, one expf).
// Phase B: lane -> (j-parity, dim-pair): 4B/lane v loads covering 2 rows per
// instruction; shfl_xor(32) folds the parity halves at the end.
// ---------------------------------------------------------------------------
__global__ __launch_bounds__(256) void attn_kernel(
    const float* __restrict__ q, const bf16* __restrict__ k,
    const bf16* __restrict__ v, const float* __restrict__ temporal,
    const unsigned int* __restrict__ mask, bf16* __restrict__ att)
{
    __shared__ int jlist[MAXDEG];
    __shared__ float qs[HIDDEN];
    __shared__ float pj[NHEAD][64];
    __shared__ int cnt;
    const int i = blockIdx.x, tid = threadIdx.x;

    if (tid == 0) cnt = 0;
    qs[tid] = q[(size_t)i * HIDDEN + tid];
    __syncthreads();
    if (tid < MASK_WORDS) {
        unsigned int bits = mask[(size_t)i * MASK_WORDS + tid];
        int n = __popc(bits);
        if (n) {
            int pos = atomicAdd(&cnt, n);
            while (bits) {
                int b = __ffs(bits) - 1;
                bits &= bits - 1;
                if (pos < MAXDEG) jlist[pos] = (tid << 5) + b;
                ++pos;
            }
        }
    }
    __syncthreads();
    const int nn = cnt;   // >= 1 (diagonal always set)

    const int h = tid >> 6, lane = tid & 63;
    const int half = lane >> 5, dpair = lane & 31;   // phase-B mapping
    const float* trow = temporal + (size_t)i * N_NODES * 2;
    const unsigned short* kp = (const unsigned short*)k;
    const unsigned short* vp = (const unsigned short*)v;
    const float* qh = qs + h * DHEAD;

    float l = 0.f, acc0 = 0.f, acc1 = 0.f;

    for (int c0 = 0; c0 < nn; c0 += 64) {
        const int cend = min(64, nn - c0);
        // ---- Phase A: lane scores neighbor jlist[c0+lane] ----
        float s = -3.0e38f;                   // exp -> 0 for invalid lanes
        if (lane < cend) {
            int j = jlist[c0 + lane];
            float dt = trow[(size_t)j * 2];
            const unsigned short* krow = kp + (size_t)j * HIDDEN + h * DHEAD;
            bf16x8 k8[8];
#pragma unroll
            for (int t = 0; t < 8; ++t)
                k8[t] = *(const bf16x8*)(krow + t * 8);
            float dot = 0.f;
#pragma unroll
            for (int t = 0; t < 8; ++t)
#pragma unroll
                for (int e = 0; e < 8; ++e)
                    dot += b2f((unsigned short)k8[t][e]) * qh[t * 8 + e];
            float tb = 0.f;
            tb += 0.2f * (float)((dt >= 0.f)  & (dt <= 5.f));
            tb += 0.1f * (float)((dt >= 5.f)  & (dt <= 15.f));
            tb -= 0.1f * (float)((dt >= 60.f) & (dt <= 240.f));
            s = dot * 0.125f + tb;
        }
        float p = __expf(s);
        float csum = p;
#pragma unroll
        for (int off = 32; off >= 1; off >>= 1)
            csum += __shfl_xor(csum, off, 64);
        pj[h][lane] = p;                      // wave-private slice, no barrier
        l += csum;
        // ---- Phase B: this lane accumulates dims {2*dpair, 2*dpair+1} of
        //      neighbors with parity `half` ----
        for (int u0 = 0; u0 < cend; u0 += 8) {
#pragma unroll
            for (int t = 0; t < 4; ++t) {
                int idx = u0 + 2 * t + half;
                bool valid = idx < cend;
                int j = jlist[c0 + (valid ? idx : 0)];
                float pv = valid ? pj[h][idx] : 0.f;
                const unsigned short* vrow = vp + (size_t)j * HIDDEN + h * DHEAD + dpair * 2;
                ushort2 v2 = *(const ushort2*)vrow;
                acc0 += pv * b2f(v2.x);
                acc1 += pv * b2f(v2.y);
            }
        }
    }

    // fold parity halves: lane L and L^32 hold the two j-parities of the same dims
    acc0 += __shfl_xor(acc0, 32, 64);
    acc1 += __shfl_xor(acc1, 32, 64);
    if (half == 0) {
        ushort2 o;
        o.x = f2bu(acc0 / l);
        o.y = f2bu(acc1 / l);
        *(ushort2*)((unsigned short*)att + (size_t)i * HIDDEN + h * DHEAD + dpair * 2) = o;
    }
}

// Dispatch 4: out = att @ Wo + bo, fp32 output
__global__ __launch_bounds__(256) void gemm_out_kernel(
    const bf16* __restrict__ att, const bf16* __restrict__ WoT,
    const float* __restrict__ bo, float* __restrict__ out)
{
    int wave = threadIdx.x >> 6;
    gemm_body<false>(att, WoT, bo, out, HIDDEN,
                     blockIdx.y * 128 + wave * 32, blockIdx.x * 16);
}

// ---------------------------------------------------------------------------
extern "C" void kernel_launch(void* const* d_in, const int* in_sizes, int n_in,
                              void* d_out, int out_size, void* d_ws, size_t ws_size,
                              hipStream_t stream) {
    const float* nf       = (const float*)d_in[0];
    const float* temporal = (const float*)d_in[1];
    const int*   eidx     = (const int*)  d_in[2];
    const float* W_in     = (const float*)d_in[3];
    const float* b_in     = (const float*)d_in[4];
    const float* Wq       = (const float*)d_in[5];
    const float* bq       = (const float*)d_in[6];
    const float* Wk       = (const float*)d_in[7];
    const float* bk       = (const float*)d_in[8];
    const float* Wv       = (const float*)d_in[9];
    const float* bv       = (const float*)d_in[10];
    const float* Wo       = (const float*)d_in[11];
    const float* bo       = (const float*)d_in[12];
    float* out = (float*)d_out;

    char* ws = (char*)d_ws;
    const size_t MiB = 1 << 20, KiB = 1 << 10;
    unsigned int* mask = (unsigned int*)(ws);                  // 2 MiB
    bf16*  nfp   = (bf16*)(ws + 2 * MiB);                      // 512 KiB
    bf16*  WqkvT = (bf16*)(ws + 2 * MiB + 512 * KiB);          // 96 KiB
    float* bqkv  = (float*)(ws + 2 * MiB + 640 * KiB);         // 3 KiB
    bf16*  WoT   = (bf16*)(ws + 3 * MiB);                      // 128 KiB
    float* q     = (float*)(ws + 4 * MiB);                     // 4 MiB
    bf16*  kb    = (bf16*)(ws + 8 * MiB);                      // 2 MiB
    bf16*  vb    = (bf16*)(ws + 10 * MiB);                     // 2 MiB
    bf16*  att   = (bf16*)(ws + 12 * MiB);                     // 2 MiB -> 14 MiB

    // 1. prep: mask zero + nf cvt + combined W'/b' + Wo transpose
    {
        int total = 131072 + N_NODES * KIN + 3 * 256 * KIN + 3 * 256 + 65536;
        prep_kernel<<<(total + 255) / 256, 256, 0, stream>>>(
            nf, W_in, b_in, Wq, bq, Wk, bk, Wv, bv, Wo,
            mask, nfp, WqkvT, bqkv, WoT);
    }

    // 2. q,k,v = nf @ W' + b' (MFMA, K=64) + edge/diag scatter
    qkv_scatter_kernel<<<1536 + 528, 256, 0, stream>>>(
        nfp, WqkvT, bqkv, eidx, q, kb, vb, mask);

    // 3. sparse masked attention
    attn_kernel<<<N_NODES, 256, 0, stream>>>(q, kb, vb, temporal, mask, att);

    // 4. out = att @ Wo + bo (MFMA)
    gemm_out_kernel<<<dim3(16, 32), 256, 0, stream>>>(att, WoT, bo, out);
}

// Round 6
// 243.940 us; speedup vs baseline: 1.5509x; 1.0135x over previous
//
#include <hip/hip_runtime.h>
#include <hip/hip_bf16.h>
#include <stdint.h>

#define N_NODES 4096
#define HIDDEN 256
#define NHEAD 4
#define DHEAD 64
#define NEDGE 131072
#define MASK_WORDS 128   // 4096 bits / 32
#define KIN 64           // combined-proj K padded 45 -> 64
#define CAP 512          // per-row neighbor cap; degree ~Poisson(33), P(>512)=0

typedef __attribute__((ext_vector_type(8))) short bf16x8;
typedef __attribute__((ext_vector_type(4))) float f32x4;
typedef __hip_bfloat16 bf16;

__device__ __forceinline__ float b2f(unsigned short s) {
    union { float f; unsigned u; } x;
    x.u = ((unsigned)s) << 16;
    return x.f;
}
__device__ __forceinline__ unsigned short f2bu(float f) {
    bf16 b = __float2bfloat16(f);
    return *(unsigned short*)&b;
}

// ---------------------------------------------------------------------------
// Dispatch 1: prep — mask zero (uint4), nf pad+cvt, combined W'/b', WoT.
// Zero->scatter ordering across the dispatch boundary (scatter in dispatch 2).
// ---------------------------------------------------------------------------
__global__ __launch_bounds__(256) void prep_kernel(
    const float* __restrict__ nf,
    const float* __restrict__ W_in, const float* __restrict__ b_in,
    const float* __restrict__ Wq, const float* __restrict__ bq,
    const float* __restrict__ Wk, const float* __restrict__ bk,
    const float* __restrict__ Wv, const float* __restrict__ bv,
    const float* __restrict__ Wo,
    unsigned int* __restrict__ mask, bf16* __restrict__ nfp,
    bf16* __restrict__ WqkvT, float* __restrict__ bqkv,
    bf16* __restrict__ WoT)
{
    int t = blockIdx.x * 256 + threadIdx.x;
    if (t < 131072) {                           // 2 MiB mask zero, 16B/thread
        ((uint4*)mask)[t] = make_uint4(0, 0, 0, 0);
        return;
    }
    t -= 131072;
    if (t < N_NODES * KIN) {                    // nfp[row][c]
        int row = t >> 6, c = t & 63;
        float v = (c < 45) ? nf[row * 45 + c] : 0.f;
        nfp[t] = __float2bfloat16(v);
        return;
    }
    t -= N_NODES * KIN;
    if (t < 3 * 256 * KIN) {                    // W'T[which][n][kk] = (W_in@W)[kk][n]
        int which = t >> 14, r = t & 16383;
        int n = r & 255, kk = r >> 8;           // consecutive t -> consecutive n
        const float* W = (which == 0) ? Wq : (which == 1) ? Wk : Wv;
        float dot = 0.f;
        if (kk < 45) {
            const float* wrow = W_in + kk * 256;   // wave-uniform reads
            for (int c = 0; c < 256; ++c)
                dot += wrow[c] * W[c * 256 + n];   // coalesced in n
        }
        WqkvT[(size_t)which * 16384 + (size_t)n * KIN + kk] = __float2bfloat16(dot);
        return;
    }
    t -= 3 * 256 * KIN;
    if (t < 3 * 256) {                          // b'[which][n] = b_in@W + b
        int which = t >> 8, n = t & 255;
        const float* W = (which == 0) ? Wq : (which == 1) ? Wk : Wv;
        const float* b = (which == 0) ? bq : (which == 1) ? bk : bv;
        float acc = b[n];
        for (int c = 0; c < 256; ++c)
            acc += b_in[c] * W[c * 256 + n];
        bqkv[t] = acc;
        return;
    }
    t -= 3 * 256;
    if (t < 65536) {                            // WoT[n][kk] = Wo[kk][n]
        int kk = t >> 8, n = t & 255;           // coalesced read of Wo
        WoT[(size_t)n * 256 + kk] = __float2bfloat16(Wo[(size_t)kk * 256 + n]);
    }
}

// ---------------------------------------------------------------------------
// bf16 MFMA GEMM body: C(M x 256) = A(M x K) @ Bt^T + bias.
// Frag layout (m89-verified): A[m=lane&15][k=quad*8+j]; D col=lane&15,
// row=quad*4+reg.
// ---------------------------------------------------------------------------
template <bool OUT_BF16>
__device__ __forceinline__ void gemm_body(
    const bf16* __restrict__ A, const bf16* __restrict__ Bt,
    const float* __restrict__ bias, void* __restrict__ Cv,
    int K, int m_base, int n0)
{
    const int lane = threadIdx.x & 63;
    const int row = lane & 15, quad = lane >> 4;
    f32x4 acc0 = {0.f, 0.f, 0.f, 0.f};
    f32x4 acc1 = {0.f, 0.f, 0.f, 0.f};
    const short* Ap = (const short*)A;
    const short* Bp = (const short*)Bt;

    for (int k0 = 0; k0 < K; k0 += 32) {
        bf16x8 b  = *(const bf16x8*)(Bp + (size_t)(n0 + row) * K + k0 + quad * 8);
        bf16x8 a0 = *(const bf16x8*)(Ap + (size_t)(m_base + row) * K + k0 + quad * 8);
        bf16x8 a1 = *(const bf16x8*)(Ap + (size_t)(m_base + 16 + row) * K + k0 + quad * 8);
        acc0 = __builtin_amdgcn_mfma_f32_16x16x32_bf16(a0, b, acc0, 0, 0, 0);
        acc1 = __builtin_amdgcn_mfma_f32_16x16x32_bf16(a1, b, acc1, 0, 0, 0);
    }

    const int col = row;
    const float bval = bias[n0 + col];
#pragma unroll
    for (int e = 0; e < 4; ++e) {
        int m0 = m_base + quad * 4 + e;
        int m1 = m0 + 16;
        float v0 = acc0[e] + bval;
        float v1 = acc1[e] + bval;
        if (OUT_BF16) {
            ((bf16*)Cv)[(size_t)m0 * HIDDEN + n0 + col] = __float2bfloat16(v0);
            ((bf16*)Cv)[(size_t)m1 * HIDDEN + n0 + col] = __float2bfloat16(v1);
        } else {
            ((float*)Cv)[(size_t)m0 * HIDDEN + n0 + col] = v0;
            ((float*)Cv)[(size_t)m1 * HIDDEN + n0 + col] = v1;
        }
    }
}

// ---------------------------------------------------------------------------
// Dispatch 2: QKV MFMA GEMM (q,k,v all bf16) + edge/diag bitmask scatter.
// Bitmask dedupes duplicate edges (must not double-count in softmax).
// ---------------------------------------------------------------------------
__global__ __launch_bounds__(256) void qkv_scatter_kernel(
    const bf16* __restrict__ nfp, const bf16* __restrict__ WqkvT,
    const float* __restrict__ bqkv, const int* __restrict__ eidx,
    bf16* __restrict__ q, bf16* __restrict__ k, bf16* __restrict__ v,
    unsigned int* __restrict__ mask)
{
    int bx = blockIdx.x;
    if (bx < 1536) {
        int ntile = bx >> 5, mrow = bx & 31;
        int which = ntile >> 4;
        const bf16* Bt = WqkvT + (size_t)which * 16384;
        const float* bias = bqkv + which * 256;
        int wave = threadIdx.x >> 6;
        int mb = mrow * 128 + wave * 32;
        int n0 = (ntile & 15) * 16;
        bf16* C = (which == 0) ? q : (which == 1) ? k : v;
        gemm_body<true>(nfp, Bt, bias, C, KIN, mb, n0);
        return;
    }
    int t = (bx - 1536) * 256 + threadIdx.x;
    if (t < NEDGE) {
        int u = eidx[t], w = eidx[NEDGE + t];
        atomicOr(&mask[u * MASK_WORDS + (w >> 5)], 1u << (w & 31));
    } else {
        int i = t - NEDGE;
        if (i < N_NODES)
            atomicOr(&mask[i * MASK_WORDS + (i >> 5)], 1u << (i & 31));
    }
}

// ---------------------------------------------------------------------------
// Dispatch 3: sparse masked attention — wave-autonomous (wave = row, all 4
// heads). No __syncthreads anywhere. jlist via shfl prefix-scan. No max-shift:
// |s| <= ~30 so exp(s) is fp32-safe; softmax shift-invariant.
// Phase A: lane = neighbor, scores all 4 heads (k row read once, dt once).
// Phase B: lane = 4-dim group (d = 4*lane), full 256-dim v row per iteration.
// ---------------------------------------------------------------------------
__global__ __launch_bounds__(256) void attn_kernel(
    const bf16* __restrict__ q, const bf16* __restrict__ k,
    const bf16* __restrict__ v, const float* __restrict__ temporal,
    const unsigned int* __restrict__ mask, bf16* __restrict__ att)
{
    __shared__ int   jl[4][CAP];       // 8 KB
    __shared__ float qsw[4][HIDDEN];   // 4 KB
    __shared__ float pch[4][4][68];    // 4.25 KB (stride 68: no 4-way h conflict)
    const int w    = threadIdx.x >> 6;
    const int lane = threadIdx.x & 63;
    const int i    = blockIdx.x * 4 + w;

    // --- stage q row (bf16 -> fp32 LDS), wave-private ---
    {
        const unsigned short* qp = (const unsigned short*)q + (size_t)i * HIDDEN + 4 * lane;
        ushort4 q4 = *(const ushort4*)qp;
        qsw[w][4 * lane + 0] = b2f(q4.x);
        qsw[w][4 * lane + 1] = b2f(q4.y);
        qsw[w][4 * lane + 2] = b2f(q4.z);
        qsw[w][4 * lane + 3] = b2f(q4.w);
    }

    // --- build jlist: lane scans mask words 2*lane, 2*lane+1; shfl scan ---
    const unsigned int* mrow = mask + (size_t)i * MASK_WORDS;
    unsigned int w0 = mrow[2 * lane], w1 = mrow[2 * lane + 1];
    int c = __popc(w0) + __popc(w1);
    int inc = c;
#pragma unroll
    for (int off = 1; off < 64; off <<= 1) {
        int tt = __shfl_up(inc, off, 64);
        if (lane >= off) inc += tt;
    }
    const int nn0 = __shfl(inc, 63, 64);
    const int nn = (nn0 < CAP) ? nn0 : CAP;
    int pos = inc - c;
    int jb = lane * 64;
    while (w0) {
        int b = __ffs(w0) - 1; w0 &= w0 - 1;
        if (pos < CAP) jl[w][pos] = jb + b;
        ++pos;
    }
    jb += 32;
    while (w1) {
        int b = __ffs(w1) - 1; w1 &= w1 - 1;
        if (pos < CAP) jl[w][pos] = jb + b;
        ++pos;
    }
    // (wave-private LDS: compiler's lgkmcnt ordering suffices, no barrier)

    const float* trow = temporal + (size_t)i * N_NODES * 2;
    const unsigned short* kp = (const unsigned short*)k;
    const unsigned short* vp = (const unsigned short*)v;
    const int hsel = lane >> 4;

    float l0 = 0.f, l1 = 0.f, l2 = 0.f, l3 = 0.f;
    float a0 = 0.f, a1 = 0.f, a2 = 0.f, a3 = 0.f;

    for (int c0 = 0; c0 < nn; c0 += 64) {
        const int cend = min(64, nn - c0);
        // ---- Phase A: lane scores neighbor jl[w][c0+lane] for all 4 heads --
        int j = (lane < cend) ? jl[w][c0 + lane] : -1;
        float tb = 0.f;
        if (j >= 0) {
            float dt = trow[(size_t)j * 2];
            tb += 0.2f * (float)((dt >= 0.f)  & (dt <= 5.f));
            tb += 0.1f * (float)((dt >= 5.f)  & (dt <= 15.f));
            tb -= 0.1f * (float)((dt >= 60.f) & (dt <= 240.f));
        }
#pragma unroll
        for (int h = 0; h < 4; ++h) {
            float dot = 0.f;
            if (j >= 0) {
                const unsigned short* krow = kp + (size_t)j * HIDDEN + h * DHEAD;
#pragma unroll
                for (int t = 0; t < 8; ++t) {
                    bf16x8 k8 = *(const bf16x8*)(krow + t * 8);
                    f32x4 qa = *(const f32x4*)(&qsw[w][h * DHEAD + t * 8]);
                    f32x4 qb = *(const f32x4*)(&qsw[w][h * DHEAD + t * 8 + 4]);
                    dot += b2f((unsigned short)k8[0]) * qa[0];
                    dot += b2f((unsigned short)k8[1]) * qa[1];
                    dot += b2f((unsigned short)k8[2]) * qa[2];
                    dot += b2f((unsigned short)k8[3]) * qa[3];
                    dot += b2f((unsigned short)k8[4]) * qb[0];
                    dot += b2f((unsigned short)k8[5]) * qb[1];
                    dot += b2f((unsigned short)k8[6]) * qb[2];
                    dot += b2f((unsigned short)k8[7]) * qb[3];
                }
            }
            float s = (j >= 0) ? dot * 0.125f + tb : -3.0e38f;
            float p = __expf(s);                // invalid lanes -> 0
            float cs = p;
#pragma unroll
            for (int off = 32; off >= 1; off >>= 1)
                cs += __shfl_xor(cs, off, 64);
            pch[w][h][lane] = p;
            if (h == 0) l0 += cs; else if (h == 1) l1 += cs;
            else if (h == 2) l2 += cs; else l3 += cs;
        }
        // ---- Phase B: lane accumulates dims [4*lane, 4*lane+4) ----
        const float* ph = pch[w][hsel];
        int jj = 0;
        for (; jj + 4 <= cend; jj += 4) {
            int ja = jl[w][c0 + jj],     jb2 = jl[w][c0 + jj + 1];
            int jc = jl[w][c0 + jj + 2], jd  = jl[w][c0 + jj + 3];
            float pa = ph[jj], pb = ph[jj + 1], pc = ph[jj + 2], pd = ph[jj + 3];
            ushort4 va = *(const ushort4*)(vp + (size_t)ja  * HIDDEN + 4 * lane);
            ushort4 vb = *(const ushort4*)(vp + (size_t)jb2 * HIDDEN + 4 * lane);
            ushort4 vc = *(const ushort4*)(vp + (size_t)jc  * HIDDEN + 4 * lane);
            ushort4 vd = *(const ushort4*)(vp + (size_t)jd  * HIDDEN + 4 * lane);
            a0 += pa * b2f(va.x) + pb * b2f(vb.x) + pc * b2f(vc.x) + pd * b2f(vd.x);
            a1 += pa * b2f(va.y) + pb * b2f(vb.y) + pc * b2f(vc.y) + pd * b2f(vd.y);
            a2 += pa * b2f(va.z) + pb * b2f(vb.z) + pc * b2f(vc.z) + pd * b2f(vd.z);
            a3 += pa * b2f(va.w) + pb * b2f(vb.w) + pc * b2f(vc.w) + pd * b2f(vd.w);
        }
        for (; jj < cend; ++jj) {
            int jx = jl[w][c0 + jj];
            float px = ph[jj];
            ushort4 vx = *(const ushort4*)(vp + (size_t)jx * HIDDEN + 4 * lane);
            a0 += px * b2f(vx.x);
            a1 += px * b2f(vx.y);
            a2 += px * b2f(vx.z);
            a3 += px * b2f(vx.w);
        }
    }

    float lsel = (hsel == 0) ? l0 : (hsel == 1) ? l1 : (hsel == 2) ? l2 : l3;
    float inv = 1.f / lsel;
    ushort4 o;
    o.x = f2bu(a0 * inv);
    o.y = f2bu(a1 * inv);
    o.z = f2bu(a2 * inv);
    o.w = f2bu(a3 * inv);
    *(ushort4*)((unsigned short*)att + (size_t)i * HIDDEN + 4 * lane) = o;
}

// Dispatch 4: out = att @ Wo + bo, fp32 output
__global__ __launch_bounds__(256) void gemm_out_kernel(
    const bf16* __restrict__ att, const bf16* __restrict__ WoT,
    const float* __restrict__ bo, float* __restrict__ out)
{
    int wave = threadIdx.x >> 6;
    gemm_body<false>(att, WoT, bo, out, HIDDEN,
                     blockIdx.y * 128 + wave * 32, blockIdx.x * 16);
}

// ---------------------------------------------------------------------------
extern "C" void kernel_launch(void* const* d_in, const int* in_sizes, int n_in,
                              void* d_out, int out_size, void* d_ws, size_t ws_size,
                              hipStream_t stream) {
    const float* nf       = (const float*)d_in[0];
    const float* temporal = (const float*)d_in[1];
    const int*   eidx     = (const int*)  d_in[2];
    const float* W_in     = (const float*)d_in[3];
    const float* b_in     = (const float*)d_in[4];
    const float* Wq       = (const float*)d_in[5];
    const float* bq       = (const float*)d_in[6];
    const float* Wk       = (const float*)d_in[7];
    const float* bk       = (const float*)d_in[8];
    const float* Wv       = (const float*)d_in[9];
    const float* bv       = (const float*)d_in[10];
    const float* Wo       = (const float*)d_in[11];
    const float* bo       = (const float*)d_in[12];
    float* out = (float*)d_out;

    char* ws = (char*)d_ws;
    const size_t MiB = 1 << 20, KiB = 1 << 10;
    unsigned int* mask = (unsigned int*)(ws);                  // 2 MiB
    bf16*  nfp   = (bf16*)(ws + 2 * MiB);                      // 512 KiB
    bf16*  WqkvT = (bf16*)(ws + 2 * MiB + 512 * KiB);          // 96 KiB
    float* bqkv  = (float*)(ws + 2 * MiB + 640 * KiB);         // 3 KiB
    bf16*  WoT   = (bf16*)(ws + 3 * MiB);                      // 128 KiB
    bf16*  qb    = (bf16*)(ws + 4 * MiB);                      // 2 MiB
    bf16*  kb    = (bf16*)(ws + 6 * MiB);                      // 2 MiB
    bf16*  vb    = (bf16*)(ws + 8 * MiB);                      // 2 MiB
    bf16*  att   = (bf16*)(ws + 10 * MiB);                     // 2 MiB -> 12 MiB

    // 1. prep: mask zero + nf cvt + combined W'/b' + Wo transpose
    {
        int total = 131072 + N_NODES * KIN + 3 * 256 * KIN + 3 * 256 + 65536;
        prep_kernel<<<(total + 255) / 256, 256, 0, stream>>>(
            nf, W_in, b_in, Wq, bq, Wk, bk, Wv, bv, Wo,
            mask, nfp, WqkvT, bqkv, WoT);
    }

    // 2. q,k,v = nf @ W' + b' (MFMA, K=64, all bf16) + edge/diag scatter
    qkv_scatter_kernel<<<1536 + 528, 256, 0, stream>>>(
        nfp, WqkvT, bqkv, eidx, qb, kb, vb, mask);

    // 3. sparse masked attention (wave = row, barrier-free)
    attn_kernel<<<N_NODES / 4, 256, 0, stream>>>(qb, kb, vb, temporal, mask, att);

    // 4. out = att @ Wo + bo (MFMA)
    gemm_out_kernel<<<dim3(16, 32), 256, 0, stream>>>(att, WoT, bo, out);
}